// Round 8
// baseline (1000499.902 us; speedup 1.0000x reference)
//
#include <hip/hip_runtime.h>
#include <stdint.h>

// RNNLayer: h_t = tanh([x_t, h_{t-1}] @ W + b), outputs all h_t [B,T,H] fp32.
// B=64, T=1024, D=1024, H=1024.  W: [D+H, H] fp32.
//
// Phase 1: XP = x @ W[:D] + b -> d_out (bf16 MFMA, 128x128 tiles).
// Phase 2: persistent scan, 4 rings x 8 WGs (same XCD), 512 thr, 16r x 128c each.
//   Round-8 exchange: producers use global_atomic_swap_x2 (atomics EXECUTE AT
//   the XCD L2 -> cannot linger in L1/WC, unlike round-7's plain stores);
//   consumers poll with sc0 loads (L1 bypass, L2 read). Startup SELF-TEST
//   exercises exactly this write+read pair per ring; a global verdict counter
//   (agent sc1) makes all 32 WGs agree: any failure -> EVERYONE runs the
//   known-good round-5 sc1 protocol from t=0 (no mixed-mode, ~10ms not 1.4s).
//   Insurance per-thread degrade dual-publishes (swap + sc1) for both reader
//   classes. Rings spread <=1/XCD; XP loads after the poll; paired-lane u64
//   swaps. Tags {step:16|bf16:16} keep correctness placement-independent.

#define T_LEN 1024
#define HID   1024
#define SCAN_WGS 256

typedef float    f32x4  __attribute__((ext_vector_type(4)));
typedef unsigned u32x4  __attribute__((ext_vector_type(4)));
typedef __bf16   bf16x8 __attribute__((ext_vector_type(8)));
typedef unsigned long long u64;

// ---------------- Phase 1: x_proj GEMM ----------------
__global__ __launch_bounds__(256) void xproj_gemm(
    const float* __restrict__ x, const float* __restrict__ W,
    const float* __restrict__ bias, float* __restrict__ out)
{
    __shared__ __align__(16) __bf16 As[128][40];
    __shared__ __align__(16) __bf16 Bs[128][40];

    const int bid = blockIdx.x;
    const int n0  = (bid & 7) << 7;
    const int64_t r0 = (int64_t)(bid >> 3) << 7;
    const int tid  = threadIdx.x;
    const int lane = tid & 63;
    const int w    = tid >> 6;
    const int hi   = lane >> 4, lo = lane & 15;
    const int wm   = (w >> 1) << 6, wn = (w & 1) << 6;

    f32x4 acc[4][4] = {};

    const int arow = tid >> 1, akh = (tid & 1) << 4;
    const int bk   = tid >> 3, bnh = (tid & 7) << 4;

    for (int k0 = 0; k0 < 1024; k0 += 32) {
        {
            const float* src = x + (r0 + arow) * 1024 + k0 + akh;
            bf16x8 t0, t1;
            #pragma unroll
            for (int i2 = 0; i2 < 8; ++i2) { t0[i2] = (__bf16)src[i2]; t1[i2] = (__bf16)src[8 + i2]; }
            *(bf16x8*)&As[arow][akh]     = t0;
            *(bf16x8*)&As[arow][akh + 8] = t1;
        }
        {
            const float* src = W + (int64_t)(k0 + bk) * 1024 + n0 + bnh;
            #pragma unroll
            for (int i2 = 0; i2 < 16; ++i2) {
                int col = bnh + i2;
                Bs[col][bk ^ (((col >> 4) & 3) << 3)] = (__bf16)src[i2];
            }
        }
        __syncthreads();

        bf16x8 af[4], bfr[4];
        #pragma unroll
        for (int f = 0; f < 4; ++f)
            af[f] = *(const bf16x8*)&As[wm + f * 16 + lo][hi << 3];
        #pragma unroll
        for (int f = 0; f < 4; ++f) {
            const int cswz = (((wn >> 4) + f) & 3) << 3;
            bfr[f] = *(const bf16x8*)&Bs[wn + f * 16 + lo][(hi << 3) ^ cswz];
        }
        #pragma unroll
        for (int fm = 0; fm < 4; ++fm)
            #pragma unroll
            for (int fn = 0; fn < 4; ++fn)
                acc[fm][fn] = __builtin_amdgcn_mfma_f32_16x16x32_bf16(af[fm], bfr[fn], acc[fm][fn], 0, 0, 0);
        __syncthreads();
    }

    #pragma unroll
    for (int fm = 0; fm < 4; ++fm) {
        const int64_t mrow = r0 + wm + fm * 16 + hi * 4;
        #pragma unroll
        for (int fn = 0; fn < 4; ++fn) {
            const int col = n0 + wn + fn * 16 + lo;
            const float bv = bias[col];
            #pragma unroll
            for (int r = 0; r < 4; ++r)
                out[(mrow + r) * 1024 + col] = acc[fm][fn][r] + bv;
        }
    }
}

// fast tanh: 1 - 2/(exp(2x)+1); saturates correctly for |x| large.
__device__ __forceinline__ float tanh_fast(float x) {
    float e = __builtin_amdgcn_exp2f(x * 2.885390082f);
    return 1.0f - 2.0f * __builtin_amdgcn_rcpf(e + 1.0f);
}

#define SWAPX2(addr, q) \
    asm volatile("global_atomic_swap_x2 %0, %1, off" :: "v"(addr), "v"(q) : "memory")

// ---------------- Phase 2: persistent recurrent scan ----------------
__global__ __launch_bounds__(512, 1) void rnn_scan(
    const float* __restrict__ W, float* __restrict__ out,
    unsigned int* hx, int* reg)
{
    __shared__ __align__(16) unsigned char A_lds[2][16 * 2048];  // dbuf 2x32KB
    __shared__ int s_role[3];

    const int tid = threadIdx.x;
    const int lane = tid & 63;
    const int wv  = tid >> 6;
    const int hi  = lane >> 4, lo = lane & 15;

    // ---- ring formation (<=1 ring per XCD) + fast-path self-test + verdict ----
    if (tid == 0) {
        unsigned xcd;
        asm volatile("s_getreg_b32 %0, hwreg(20, 0, 32)" : "=s"(xcd));  // HW_REG_XCC_ID
        xcd &= 7;
        int rank = __hip_atomic_fetch_add(&reg[xcd], 1, __ATOMIC_RELAXED, __HIP_MEMORY_SCOPE_AGENT);
        __hip_atomic_fetch_add(&reg[8], 1, __ATOMIC_RELEASE, __HIP_MEMORY_SCOPE_AGENT);
        while (__hip_atomic_load(&reg[8], __ATOMIC_ACQUIRE, __HIP_MEMORY_SCOPE_AGENT) < SCAN_WGS)
            __builtin_amdgcn_s_sleep(8);
        int cnt[8];
        #pragma unroll
        for (int xx = 0; xx < 8; ++xx)
            cnt[xx] = __hip_atomic_load(&reg[xx], __ATOMIC_RELAXED, __HIP_MEMORY_SCOPE_AGENT);
        // round-robin over XCDs: ring r hosted by r-th (xcd,group) in enumeration
        int R = 0, ring = -1, slot = 0;
        for (int round = 0; round < 4 && R < 4; ++round)
            for (int xx = 0; xx < 8 && R < 4; ++xx)
                if ((cnt[xx] >> 3) > round) {
                    if (xx == (int)xcd && (rank >> 3) == round) { ring = R; slot = rank & 7; }
                    ++R;
                }
        int panic = 0;
        if (ring >= 0) {
            // self-test: L2 atomic add + sc0 load — the exact main-loop mechanisms
            unsigned long long ca = (unsigned long long)(uintptr_t)(reg + 12 + ring);
            unsigned one = 1;
            asm volatile("global_atomic_add %0, %1, off" :: "v"(ca), "v"(one) : "memory");
            bool ok = false;
            for (int it = 0; it < (1 << 13); ++it) {
                unsigned cur;
                asm volatile("global_load_dword %0, %1, off sc0\n\ts_waitcnt vmcnt(0)"
                             : "=v"(cur) : "v"(ca) : "memory");
                if (cur >= 8) { ok = true; break; }
                __builtin_amdgcn_s_sleep(2);
            }
            if (ok) __hip_atomic_fetch_add(&reg[16], 1, __ATOMIC_RELAXED, __HIP_MEMORY_SCOPE_AGENT);
            // global verdict: need all 32 assigned WGs ok, else EVERYONE panics
            int v = 0;
            for (int it = 0; it < (1 << 11); ++it) {
                v = __hip_atomic_load(&reg[16], __ATOMIC_RELAXED, __HIP_MEMORY_SCOPE_AGENT);
                if (v >= 32) break;
                __builtin_amdgcn_s_sleep(32);
            }
            if (v < 32) panic = 1;
        }
        s_role[0] = ring; s_role[1] = slot; s_role[2] = panic;
    }
    __syncthreads();
    const int ig = s_role[0];        // ring -> batch rows 16*ig..+15
    const int jg = s_role[1];        // slot -> hidden cols 128*jg..+127
    bool degr   = (s_role[2] != 0);  // sc1 agent protocol (known-good round-5)
    if (ig < 0) return;

    // ---- one-time: Wh B-frags for this wave's 16 cols, ALL K, in registers ----
    const int col = jg * 128 + wv * 16 + lo;
    bf16x8 breg[32];
    {
        const float* wb = W + (int64_t)1024 * 1024 + col;
        #pragma unroll
        for (int kb = 0; kb < 32; ++kb) {
            const float* src = wb + (int64_t)(kb * 32 + hi * 8) * 1024;
            bf16x8 tf;
            #pragma unroll
            for (int j = 0; j < 8; ++j) tf[j] = (__bf16)src[(int64_t)j * 1024];
            breg[kb] = tf;
        }
    }

    // staging role: 16 rows x 32 threads/row, 16 u64 (32 cols) each
    const int srow = tid >> 5;
    const int c32  = tid & 31;
    const unsigned slab_byte = (unsigned)(((ig * 16 + srow) * 512 + c32 * 16) * 8);
    const unsigned swz_w  = (unsigned)((srow & 7) << 4);
    const unsigned kbyte0 = (unsigned)(c32 * 64);

    // compute role: A-frag read base
    const unsigned abase = (unsigned)(lo * 2048);
    const unsigned axor  = (unsigned)((lo & 7) << 4);

    const int64_t rstride = (int64_t)T_LEN * HID;
    float* pr0 = out + (int64_t)(ig * 16 + hi * 4) * rstride + col;
    const int wr0 = (ig * 16 + hi * 4) * 1024 + col;

    // swap addresses (even-lo lanes write u64 {col,col+1} per row), 2 slots x 4 rows
    const unsigned cw = (unsigned)(wr0 & ~1);
    const unsigned long long aE0 = (unsigned long long)(uintptr_t)(hx + cw);
    const unsigned long long aE1 = aE0 + 4096, aE2 = aE0 + 8192, aE3 = aE0 + 12288;
    const unsigned long long aO0 = (unsigned long long)(uintptr_t)(hx + 65536 + cw);
    const unsigned long long aO1 = aO0 + 4096, aO2 = aO0 + 8192, aO3 = aO0 + 12288;

    unsigned svE0 = 0, svE1 = 0, svE2 = 0, svE3 = 0;   // last stores, slot 0 (even t)
    unsigned svO0 = 0, svO1 = 0, svO2 = 0, svO3 = 0;   // slot 1 (odd t)

    for (int t = 0; t < T_LEN; ++t) {
        float xpv0, xpv1, xpv2, xpv3;

        if (t > 0) {
            const unsigned exptag = (unsigned)t;
            const unsigned* sbase = hx + ((t - 1) & 1) * 65536;
            u32x4 r0, r1, r2, r3, r4, r5, r6, r7;
            unsigned retries = 0;
            for (;;) {
                if (!degr) {
                    asm volatile(
                        "global_load_dwordx4 %0, %8, %9 offset:0 sc0\n\t"
                        "global_load_dwordx4 %1, %8, %9 offset:16 sc0\n\t"
                        "global_load_dwordx4 %2, %8, %9 offset:32 sc0\n\t"
                        "global_load_dwordx4 %3, %8, %9 offset:48 sc0\n\t"
                        "global_load_dwordx4 %4, %8, %9 offset:64 sc0\n\t"
                        "global_load_dwordx4 %5, %8, %9 offset:80 sc0\n\t"
                        "global_load_dwordx4 %6, %8, %9 offset:96 sc0\n\t"
                        "global_load_dwordx4 %7, %8, %9 offset:112 sc0\n\t"
                        "s_waitcnt vmcnt(0)"
                        : "=&v"(r0), "=&v"(r1), "=&v"(r2), "=&v"(r3),
                          "=&v"(r4), "=&v"(r5), "=&v"(r6), "=&v"(r7)
                        : "v"(slab_byte), "s"(sbase) : "memory");
                } else {
                    const u64* bp = (const u64*)sbase + (slab_byte >> 3);
                    u64 q[16];
                    #pragma unroll
                    for (int j = 0; j < 16; ++j)
                        q[j] = __hip_atomic_load(bp + j, __ATOMIC_RELAXED, __HIP_MEMORY_SCOPE_AGENT);
                    r0 = u32x4{(unsigned)q[0], (unsigned)(q[0] >> 32), (unsigned)q[1], (unsigned)(q[1] >> 32)};
                    r1 = u32x4{(unsigned)q[2], (unsigned)(q[2] >> 32), (unsigned)q[3], (unsigned)(q[3] >> 32)};
                    r2 = u32x4{(unsigned)q[4], (unsigned)(q[4] >> 32), (unsigned)q[5], (unsigned)(q[5] >> 32)};
                    r3 = u32x4{(unsigned)q[6], (unsigned)(q[6] >> 32), (unsigned)q[7], (unsigned)(q[7] >> 32)};
                    r4 = u32x4{(unsigned)q[8], (unsigned)(q[8] >> 32), (unsigned)q[9], (unsigned)(q[9] >> 32)};
                    r5 = u32x4{(unsigned)q[10], (unsigned)(q[10] >> 32), (unsigned)q[11], (unsigned)(q[11] >> 32)};
                    r6 = u32x4{(unsigned)q[12], (unsigned)(q[12] >> 32), (unsigned)q[13], (unsigned)(q[13] >> 32)};
                    r7 = u32x4{(unsigned)q[14], (unsigned)(q[14] >> 32), (unsigned)q[15], (unsigned)(q[15] >> 32)};
                }
                unsigned badm = 0;
                #define CKTAG(rr) badm |= ((rr.x >> 16) ^ exptag) | ((rr.y >> 16) ^ exptag) \
                                        | ((rr.z >> 16) ^ exptag) | ((rr.w >> 16) ^ exptag)
                CKTAG(r0); CKTAG(r1); CKTAG(r2); CKTAG(r3);
                CKTAG(r4); CKTAG(r5); CKTAG(r6); CKTAG(r7);
                #undef CKTAG
                if (!badm) break;
                if (!degr && ++retries > (1u << 16)) {
                    // insurance: switch self to sc1 + republish BOTH slots
                    degr = true;
                    __hip_atomic_store(hx + wr0,                 svE0, __ATOMIC_RELAXED, __HIP_MEMORY_SCOPE_AGENT);
                    __hip_atomic_store(hx + wr0 + 1024,          svE1, __ATOMIC_RELAXED, __HIP_MEMORY_SCOPE_AGENT);
                    __hip_atomic_store(hx + wr0 + 2048,          svE2, __ATOMIC_RELAXED, __HIP_MEMORY_SCOPE_AGENT);
                    __hip_atomic_store(hx + wr0 + 3072,          svE3, __ATOMIC_RELAXED, __HIP_MEMORY_SCOPE_AGENT);
                    __hip_atomic_store(hx + 65536 + wr0,         svO0, __ATOMIC_RELAXED, __HIP_MEMORY_SCOPE_AGENT);
                    __hip_atomic_store(hx + 65536 + wr0 + 1024,  svO1, __ATOMIC_RELAXED, __HIP_MEMORY_SCOPE_AGENT);
                    __hip_atomic_store(hx + 65536 + wr0 + 2048,  svO2, __ATOMIC_RELAXED, __HIP_MEMORY_SCOPE_AGENT);
                    __hip_atomic_store(hx + 65536 + wr0 + 3072,  svO3, __ATOMIC_RELAXED, __HIP_MEMORY_SCOPE_AGENT);
                }
                if (degr) { __builtin_amdgcn_s_sleep(16); }
                else      { __builtin_amdgcn_s_sleep(1);  }
            }

            // XP loads here: overlap HBM latency with stage+barrier+MFMA
            xpv0 = pr0[(int64_t)t * HID];
            xpv1 = pr0[(int64_t)t * HID + rstride];
            xpv2 = pr0[(int64_t)t * HID + 2 * rstride];
            xpv3 = pr0[(int64_t)t * HID + 3 * rstride];

            // unpack {tag|bf16}x2 -> packed bf16x2 dwords, write swizzled LDS (dbuf t&1)
            unsigned dwp[16];
            dwp[0]  = __builtin_amdgcn_perm(r0.y, r0.x, 0x05040100u);
            dwp[1]  = __builtin_amdgcn_perm(r0.w, r0.z, 0x05040100u);
            dwp[2]  = __builtin_amdgcn_perm(r1.y, r1.x, 0x05040100u);
            dwp[3]  = __builtin_amdgcn_perm(r1.w, r1.z, 0x05040100u);
            dwp[4]  = __builtin_amdgcn_perm(r2.y, r2.x, 0x05040100u);
            dwp[5]  = __builtin_amdgcn_perm(r2.w, r2.z, 0x05040100u);
            dwp[6]  = __builtin_amdgcn_perm(r3.y, r3.x, 0x05040100u);
            dwp[7]  = __builtin_amdgcn_perm(r3.w, r3.z, 0x05040100u);
            dwp[8]  = __builtin_amdgcn_perm(r4.y, r4.x, 0x05040100u);
            dwp[9]  = __builtin_amdgcn_perm(r4.w, r4.z, 0x05040100u);
            dwp[10] = __builtin_amdgcn_perm(r5.y, r5.x, 0x05040100u);
            dwp[11] = __builtin_amdgcn_perm(r5.w, r5.z, 0x05040100u);
            dwp[12] = __builtin_amdgcn_perm(r6.y, r6.x, 0x05040100u);
            dwp[13] = __builtin_amdgcn_perm(r6.w, r6.z, 0x05040100u);
            dwp[14] = __builtin_amdgcn_perm(r7.y, r7.x, 0x05040100u);
            dwp[15] = __builtin_amdgcn_perm(r7.w, r7.z, 0x05040100u);
            unsigned char* Ab = &A_lds[t & 1][0];
            #pragma unroll
            for (int i = 0; i < 4; ++i) {
                f32x4 v = { __builtin_bit_cast(float, dwp[4 * i]),
                            __builtin_bit_cast(float, dwp[4 * i + 1]),
                            __builtin_bit_cast(float, dwp[4 * i + 2]),
                            __builtin_bit_cast(float, dwp[4 * i + 3]) };
                *(f32x4*)(Ab + srow * 2048 + ((kbyte0 + 16 * i) ^ swz_w)) = v;
            }
        } else {
            xpv0 = pr0[0]; xpv1 = pr0[rstride]; xpv2 = pr0[2 * rstride]; xpv3 = pr0[3 * rstride];
        }

        __syncthreads();   // A_lds[t&1] ready; also guards buffer reuse (2-step distance)

        f32x4 accs = {0.f, 0.f, 0.f, 0.f};
        if (t > 0) {
            const unsigned char* Ab = &A_lds[t & 1][0];
            f32x4 acc0 = {0.f, 0.f, 0.f, 0.f}, acc1 = {0.f, 0.f, 0.f, 0.f};
            #pragma unroll
            for (int kb = 0; kb < 32; kb += 2) {
                bf16x8 a0 = *(const bf16x8*)(Ab + abase + (((unsigned)(kb * 64) + hi * 16) ^ axor));
                bf16x8 a1 = *(const bf16x8*)(Ab + abase + (((unsigned)((kb + 1) * 64) + hi * 16) ^ axor));
                acc0 = __builtin_amdgcn_mfma_f32_16x16x32_bf16(a0, breg[kb],     acc0, 0, 0, 0);
                acc1 = __builtin_amdgcn_mfma_f32_16x16x32_bf16(a1, breg[kb + 1], acc1, 0, 0, 0);
            }
            accs = acc0 + acc1;
        }

        float h0 = tanh_fast(xpv0 + accs[0]);
        float h1 = tanh_fast(xpv1 + accs[1]);
        float h2 = tanh_fast(xpv2 + accs[2]);
        float h3 = tanh_fast(xpv3 + accs[3]);

        const unsigned tagw = (unsigned)(t + 1) << 16;
        unsigned v0 = tagw | __builtin_bit_cast(unsigned short, (__bf16)h0);
        unsigned v1 = tagw | __builtin_bit_cast(unsigned short, (__bf16)h1);
        unsigned v2 = tagw | __builtin_bit_cast(unsigned short, (__bf16)h2);
        unsigned v3 = tagw | __builtin_bit_cast(unsigned short, (__bf16)h3);

        // L2-executed exchange: pair lanes, even-lo lanes swap u64 {col, col+1}
        unsigned p0 = (unsigned)__shfl_xor((int)v0, 1);
        unsigned p1 = (unsigned)__shfl_xor((int)v1, 1);
        unsigned p2 = (unsigned)__shfl_xor((int)v2, 1);
        unsigned p3 = (unsigned)__shfl_xor((int)v3, 1);
        if ((lo & 1) == 0) {
            u64 q0 = (u64)v0 | ((u64)p0 << 32);
            u64 q1 = (u64)v1 | ((u64)p1 << 32);
            u64 q2 = (u64)v2 | ((u64)p2 << 32);
            u64 q3 = (u64)v3 | ((u64)p3 << 32);
            if (t & 1) { SWAPX2(aO0, q0); SWAPX2(aO1, q1); SWAPX2(aO2, q2); SWAPX2(aO3, q3); }
            else       { SWAPX2(aE0, q0); SWAPX2(aE1, q1); SWAPX2(aE2, q2); SWAPX2(aE3, q3); }
        }
        if (degr) {   // also publish agent-visible for sc1 readers
            __hip_atomic_store(hx + (t & 1) * 65536 + wr0,        v0, __ATOMIC_RELAXED, __HIP_MEMORY_SCOPE_AGENT);
            __hip_atomic_store(hx + (t & 1) * 65536 + wr0 + 1024, v1, __ATOMIC_RELAXED, __HIP_MEMORY_SCOPE_AGENT);
            __hip_atomic_store(hx + (t & 1) * 65536 + wr0 + 2048, v2, __ATOMIC_RELAXED, __HIP_MEMORY_SCOPE_AGENT);
            __hip_atomic_store(hx + (t & 1) * 65536 + wr0 + 3072, v3, __ATOMIC_RELAXED, __HIP_MEMORY_SCOPE_AGENT);
        }
        if (t & 1) { svO0 = v0; svO1 = v1; svO2 = v2; svO3 = v3; }
        else       { svE0 = v0; svE1 = v1; svE2 = v2; svE3 = v3; }

        pr0[(int64_t)t * HID]               = h0;   // fp32 outputs
        pr0[(int64_t)t * HID + rstride]     = h1;
        pr0[(int64_t)t * HID + 2 * rstride] = h2;
        pr0[(int64_t)t * HID + 3 * rstride] = h3;
    }
}

extern "C" void kernel_launch(void* const* d_in, const int* in_sizes, int n_in,
                              void* d_out, int out_size, void* d_ws, size_t ws_size,
                              hipStream_t stream)
{
    const float* x    = (const float*)d_in[0];   // [64,1024,1024]
    const float* W    = (const float*)d_in[1];   // [2048,1024]
    const float* bias = (const float*)d_in[2];   // [1024]
    float* out = (float*)d_out;                  // [64,1024,1024]

    unsigned int* hx  = (unsigned int*)d_ws;                // 2 slots x 64x1024 u32 = 512 KB
    int*          reg = (int*)((char*)d_ws + 524288);       // [0..7] xcd cnt, [8] done,
                                                            // [12..15] ringchk, [16] okcnt
    (void)hipMemsetAsync(d_ws, 0, 524288 + 128, stream);
    xproj_gemm<<<dim3(4096), dim3(256), 0, stream>>>(x, W, bias, out);
    rnn_scan<<<dim3(SCAN_WGS), dim3(512), 0, stream>>>(W, out, hx, reg);
}

// Round 9
// 8489.647 us; speedup vs baseline: 117.8494x; 117.8494x over previous
//
#include <hip/hip_runtime.h>
#include <stdint.h>

// RNNLayer: h_t = tanh([x_t, h_{t-1}] @ W + b), outputs all h_t [B,T,H] fp32.
// B=64, T=1024, D=1024, H=1024.  W: [D+H, H] fp32.
//
// Phase 1: XP = x @ W[:D] + b -> d_out (bf16 MFMA, 128x128 tiles).
// Phase 2: persistent scan, 32 WGs = 4 rings x 8 col-groups, 512 thr,
//   16 rows x 128 cols per WG, Wh register-resident (128 VGPR B-frags).
//   All exchange on the PROVEN agent-scope sc1 path (rounds 3-5; the same-XCD
//   L2 experiments of rounds 6-8 showed no prompt cross-CU visibility exists
//   outside it). Round-9 changes against round 5 (7.4us/step):
//   (a) FLAG-based release: producer drains data stores (s_waitcnt vmcnt(0)
//       + barrier) then tid0 publishes ONE flag word = t+1. Only tid0 polls
//       the 8 ring flags (32 B/iter instead of 16K threads re-reading 2-16
//       MB/step through the coherent point - the suspected MALL flood behind
//       round 5's ~5.5us observe latency). Data is then loaded ONCE,
//       tag-validated (tags kept as a safety net -> worst case = round-5
//       behavior, no new failure mode).
//   (b) Conflict-free A_lds: [kb][slot^(kb&7)] layout makes both staged
//       writes and per-kb ds_read_b128 cover each 1024B window exactly once
//       (round 5 measured 58.7M conflict-cycles: 8-way-conflicted reads).
//   (c) 4 MFMA accumulators; fp32 out stores after flag publication.

#define T_LEN 1024
#define HID   1024

typedef float    f32x4  __attribute__((ext_vector_type(4)));
typedef __bf16   bf16x8 __attribute__((ext_vector_type(8)));
typedef unsigned long long u64;

// ---------------- Phase 1: x_proj GEMM ----------------
__global__ __launch_bounds__(256) void xproj_gemm(
    const float* __restrict__ x, const float* __restrict__ W,
    const float* __restrict__ bias, float* __restrict__ out)
{
    __shared__ __align__(16) __bf16 As[128][40];
    __shared__ __align__(16) __bf16 Bs[128][40];

    const int bid = blockIdx.x;
    const int n0  = (bid & 7) << 7;
    const int64_t r0 = (int64_t)(bid >> 3) << 7;
    const int tid  = threadIdx.x;
    const int lane = tid & 63;
    const int w    = tid >> 6;
    const int hi   = lane >> 4, lo = lane & 15;
    const int wm   = (w >> 1) << 6, wn = (w & 1) << 6;

    f32x4 acc[4][4] = {};

    const int arow = tid >> 1, akh = (tid & 1) << 4;
    const int bk   = tid >> 3, bnh = (tid & 7) << 4;

    for (int k0 = 0; k0 < 1024; k0 += 32) {
        {
            const float* src = x + (r0 + arow) * 1024 + k0 + akh;
            bf16x8 t0, t1;
            #pragma unroll
            for (int i2 = 0; i2 < 8; ++i2) { t0[i2] = (__bf16)src[i2]; t1[i2] = (__bf16)src[8 + i2]; }
            *(bf16x8*)&As[arow][akh]     = t0;
            *(bf16x8*)&As[arow][akh + 8] = t1;
        }
        {
            const float* src = W + (int64_t)(k0 + bk) * 1024 + n0 + bnh;
            #pragma unroll
            for (int i2 = 0; i2 < 16; ++i2) {
                int col = bnh + i2;
                Bs[col][bk ^ (((col >> 4) & 3) << 3)] = (__bf16)src[i2];
            }
        }
        __syncthreads();

        bf16x8 af[4], bfr[4];
        #pragma unroll
        for (int f = 0; f < 4; ++f)
            af[f] = *(const bf16x8*)&As[wm + f * 16 + lo][hi << 3];
        #pragma unroll
        for (int f = 0; f < 4; ++f) {
            const int cswz = (((wn >> 4) + f) & 3) << 3;
            bfr[f] = *(const bf16x8*)&Bs[wn + f * 16 + lo][(hi << 3) ^ cswz];
        }
        #pragma unroll
        for (int fm = 0; fm < 4; ++fm)
            #pragma unroll
            for (int fn = 0; fn < 4; ++fn)
                acc[fm][fn] = __builtin_amdgcn_mfma_f32_16x16x32_bf16(af[fm], bfr[fn], acc[fm][fn], 0, 0, 0);
        __syncthreads();
    }

    #pragma unroll
    for (int fm = 0; fm < 4; ++fm) {
        const int64_t mrow = r0 + wm + fm * 16 + hi * 4;
        #pragma unroll
        for (int fn = 0; fn < 4; ++fn) {
            const int col = n0 + wn + fn * 16 + lo;
            const float bv = bias[col];
            #pragma unroll
            for (int r = 0; r < 4; ++r)
                out[(mrow + r) * 1024 + col] = acc[fm][fn][r] + bv;
        }
    }
}

// fast tanh: 1 - 2/(exp(2x)+1); saturates correctly for |x| large.
__device__ __forceinline__ float tanh_fast(float x) {
    float e = __builtin_amdgcn_exp2f(x * 2.885390082f);
    return 1.0f - 2.0f * __builtin_amdgcn_rcpf(e + 1.0f);
}

// ---------------- Phase 2: persistent recurrent scan ----------------
// 32 WGs = 4 rings (16 batch rows) x 8 col-groups (128 cols). 512 threads.
__global__ __launch_bounds__(512, 1) void rnn_scan(
    const float* __restrict__ W, float* __restrict__ out,
    unsigned int* hx, unsigned int* flg)
{
    // A_lds[kb][slot^(kb&7)]: kb window = 1024 B (64 slots x 16 B),
    // slot = hi*16 + row. Single buffer (barriers make dbuf unnecessary).
    __shared__ __align__(16) unsigned char A_lds[32 * 1024];

    const int bid = blockIdx.x;
    const int ig  = bid >> 3;        // ring: batch rows 16*ig..+15
    const int jg  = bid & 7;         // col group: hidden cols 128*jg..+127
    const int tid = threadIdx.x;
    const int lane = tid & 63;
    const int wv  = tid >> 6;        // wave -> 16-col tile
    const int hi  = lane >> 4, lo = lane & 15;

    // ---- one-time: Wh B-frags for this wave's 16 cols, ALL K, in registers ----
    const int col = jg * 128 + wv * 16 + lo;
    bf16x8 breg[32];
    {
        const float* wb = W + (int64_t)1024 * 1024 + col;   // Wh starts at row 1024
        #pragma unroll
        for (int kb = 0; kb < 32; ++kb) {
            const float* src = wb + (int64_t)(kb * 32 + hi * 8) * 1024;
            bf16x8 tf;
            #pragma unroll
            for (int j = 0; j < 8; ++j) tf[j] = (__bf16)src[(int64_t)j * 1024];
            breg[kb] = tf;
        }
    }

    // staging role: 16 rows x 32 threads/row, 16 u64 (= 32 cols, kb=c32) each
    const int srow = tid >> 5;       // 0..15
    const int c32  = tid & 31;       // 0..31 == kb this thread stages
    const int slab_u64 = (ig * 16 + srow) * 512 + c32 * 16;
    const unsigned wbase = (unsigned)(c32 * 1024);      // LDS kb-window base
    const unsigned wswz  = (unsigned)(c32 & 7);

    const int64_t rstride = (int64_t)T_LEN * HID;
    float* pr0 = out + (int64_t)(ig * 16 + hi * 4) * rstride + col;
    const int wr0 = (ig * 16 + hi * 4) * 1024 + col;
    const int myflag = ig * 8 + jg;

    for (int t = 0; t < T_LEN; ++t) {
        f32x4 accs = {0.f, 0.f, 0.f, 0.f};
        float xpv0, xpv1, xpv2, xpv3;

        if (t > 0) {
            const unsigned exptag = (unsigned)t;

            // 1) ONLY tid0 polls the ring's 8 producer flags (32 B/iteration)
            if (tid == 0) {
                const u64* fp = (const u64*)(flg + (((t - 1) & 1) * 32 + ig * 8));
                const u64 expq = ((u64)exptag << 32) | (u64)exptag;
                for (;;) {
                    u64 f0 = __hip_atomic_load(fp + 0, __ATOMIC_RELAXED, __HIP_MEMORY_SCOPE_AGENT);
                    u64 f1 = __hip_atomic_load(fp + 1, __ATOMIC_RELAXED, __HIP_MEMORY_SCOPE_AGENT);
                    u64 f2 = __hip_atomic_load(fp + 2, __ATOMIC_RELAXED, __HIP_MEMORY_SCOPE_AGENT);
                    u64 f3 = __hip_atomic_load(fp + 3, __ATOMIC_RELAXED, __HIP_MEMORY_SCOPE_AGENT);
                    if (((f0 ^ expq) | (f1 ^ expq) | (f2 ^ expq) | (f3 ^ expq)) == 0) break;
                    __builtin_amdgcn_s_sleep(1);
                }
            }
            __syncthreads();   // A: flags observed -> slab is at the coherent point

            // 2) one-shot slab load (tag check = safety net; normally passes 1st try)
            const u64* bp = (const u64*)(hx + ((t - 1) & 1) * 65536) + slab_u64;
            u64 q[16];
            for (;;) {
                #pragma unroll
                for (int j = 0; j < 16; ++j)
                    q[j] = __hip_atomic_load(bp + j, __ATOMIC_RELAXED, __HIP_MEMORY_SCOPE_AGENT);
                unsigned badm = 0;
                #pragma unroll
                for (int j = 0; j < 16; ++j) {
                    badm |= ((unsigned)(q[j] >> 16) & 0xffffu) ^ exptag;
                    badm |= ((unsigned)(q[j] >> 48)) ^ exptag;
                }
                if (!badm) break;
                __builtin_amdgcn_s_sleep(1);
            }

            // XP loads here: HBM latency hides under unpack+barrier+MFMA
            xpv0 = pr0[(int64_t)t * HID];
            xpv1 = pr0[(int64_t)t * HID + rstride];
            xpv2 = pr0[(int64_t)t * HID + 2 * rstride];
            xpv3 = pr0[(int64_t)t * HID + 3 * rstride];

            // 3) unpack {tag|bf16}x2 -> bf16x2 dwords; conflict-free swizzled write
            unsigned dwp[16];
            #pragma unroll
            for (int j = 0; j < 16; ++j)
                dwp[j] = __builtin_amdgcn_perm((unsigned)(q[j] >> 32), (unsigned)q[j], 0x05040100u);
            #pragma unroll
            for (int i = 0; i < 4; ++i) {
                f32x4 v = { __builtin_bit_cast(float, dwp[4 * i]),
                            __builtin_bit_cast(float, dwp[4 * i + 1]),
                            __builtin_bit_cast(float, dwp[4 * i + 2]),
                            __builtin_bit_cast(float, dwp[4 * i + 3]) };
                *(f32x4*)(A_lds + wbase + ((((unsigned)(i * 16 + srow)) ^ wswz) << 4)) = v;
            }
            __syncthreads();   // B: A slab staged

            // 4) full-K MFMA vs register Wh; conflict-free reads; 4 accumulators
            f32x4 a0 = {0.f,0.f,0.f,0.f}, a1 = a0, a2 = a0, a3 = a0;
            #pragma unroll
            for (int kb = 0; kb < 32; kb += 4) {
                bf16x8 x0 = *(const bf16x8*)(A_lds + (unsigned)(kb + 0) * 1024 + ((((unsigned)lane) ^ (unsigned)((kb + 0) & 7)) << 4));
                bf16x8 x1 = *(const bf16x8*)(A_lds + (unsigned)(kb + 1) * 1024 + ((((unsigned)lane) ^ (unsigned)((kb + 1) & 7)) << 4));
                bf16x8 x2 = *(const bf16x8*)(A_lds + (unsigned)(kb + 2) * 1024 + ((((unsigned)lane) ^ (unsigned)((kb + 2) & 7)) << 4));
                bf16x8 x3 = *(const bf16x8*)(A_lds + (unsigned)(kb + 3) * 1024 + ((((unsigned)lane) ^ (unsigned)((kb + 3) & 7)) << 4));
                a0 = __builtin_amdgcn_mfma_f32_16x16x32_bf16(x0, breg[kb + 0], a0, 0, 0, 0);
                a1 = __builtin_amdgcn_mfma_f32_16x16x32_bf16(x1, breg[kb + 1], a1, 0, 0, 0);
                a2 = __builtin_amdgcn_mfma_f32_16x16x32_bf16(x2, breg[kb + 2], a2, 0, 0, 0);
                a3 = __builtin_amdgcn_mfma_f32_16x16x32_bf16(x3, breg[kb + 3], a3, 0, 0, 0);
            }
            accs = (a0 + a1) + (a2 + a3);
        } else {
            xpv0 = pr0[0]; xpv1 = pr0[rstride]; xpv2 = pr0[2 * rstride]; xpv3 = pr0[3 * rstride];
        }

        float h0 = tanh_fast(xpv0 + accs[0]);
        float h1 = tanh_fast(xpv1 + accs[1]);
        float h2 = tanh_fast(xpv2 + accs[2]);
        float h3 = tanh_fast(xpv3 + accs[3]);

        // exchange stores (sc1, tagged), then RELEASE: drain + barrier + flag
        const unsigned tagw = (unsigned)(t + 1) << 16;
        unsigned v0 = tagw | __builtin_bit_cast(unsigned short, (__bf16)h0);
        unsigned v1 = tagw | __builtin_bit_cast(unsigned short, (__bf16)h1);
        unsigned v2 = tagw | __builtin_bit_cast(unsigned short, (__bf16)h2);
        unsigned v3 = tagw | __builtin_bit_cast(unsigned short, (__bf16)h3);
        unsigned int* hxs = hx + (t & 1) * 65536 + wr0;
        __hip_atomic_store(hxs,        v0, __ATOMIC_RELAXED, __HIP_MEMORY_SCOPE_AGENT);
        __hip_atomic_store(hxs + 1024, v1, __ATOMIC_RELAXED, __HIP_MEMORY_SCOPE_AGENT);
        __hip_atomic_store(hxs + 2048, v2, __ATOMIC_RELAXED, __HIP_MEMORY_SCOPE_AGENT);
        __hip_atomic_store(hxs + 3072, v3, __ATOMIC_RELAXED, __HIP_MEMORY_SCOPE_AGENT);
        asm volatile("s_waitcnt vmcnt(0)" ::: "memory");   // stores at coherent point
        __syncthreads();   // C: ALL threads' stores drained
        if (tid == 0)
            __hip_atomic_store(&flg[(t & 1) * 32 + myflag], (unsigned)(t + 1),
                               __ATOMIC_RELAXED, __HIP_MEMORY_SCOPE_AGENT);

        // private epilogue off the critical path
        pr0[(int64_t)t * HID]               = h0;
        pr0[(int64_t)t * HID + rstride]     = h1;
        pr0[(int64_t)t * HID + 2 * rstride] = h2;
        pr0[(int64_t)t * HID + 3 * rstride] = h3;
    }
}

extern "C" void kernel_launch(void* const* d_in, const int* in_sizes, int n_in,
                              void* d_out, int out_size, void* d_ws, size_t ws_size,
                              hipStream_t stream)
{
    const float* x    = (const float*)d_in[0];   // [64,1024,1024]
    const float* W    = (const float*)d_in[1];   // [2048,1024]
    const float* bias = (const float*)d_in[2];   // [1024]
    float* out = (float*)d_out;                  // [64,1024,1024]

    unsigned int* hx  = (unsigned int*)d_ws;                  // 2 slots x 64x1024 u32 = 512 KB
    unsigned int* flg = (unsigned int*)((char*)d_ws + 524288);// 2 slots x 32 flags = 256 B

    (void)hipMemsetAsync(d_ws, 0, 524288 + 256, stream);      // zero tags + flags
    xproj_gemm<<<dim3(4096), dim3(256), 0, stream>>>(x, W, bias, out);
    rnn_scan<<<dim3(32), dim3(512), 0, stream>>>(W, out, hx, flg);
}